// Round 9
// baseline (780.151 us; speedup 1.0000x reference)
//
#include <hip/hip_runtime.h>

#define D      128
#define NCLI   100000
#define NAGG   1000
#define NLAYER 3
#define NBKT   782   // ceil(NCLI/128)
#define NHIST  512
#define NCVTX  (NCLI * D / 4 / 256)   // 12500
#define NCVTW  ((NLAYER * D * D + 255) / 256)  // 192

typedef short bf16x8 __attribute__((ext_vector_type(8)));
typedef float f32x4 __attribute__((ext_vector_type(4)));

static __device__ __forceinline__ float leaky(float x) { return x >= 0.f ? x : 0.1f * x; }

// ---- bf16 pack/unpack (RNE) ----
static __device__ __forceinline__ unsigned bf16_rn(float f) {
    unsigned u = __float_as_uint(f);
    return (u + 0x7fffu + ((u >> 16) & 1u)) >> 16;
}
static __device__ __forceinline__ float bf_val(unsigned h) { return __uint_as_float(h << 16); }
static __device__ __forceinline__ unsigned pack_bf2(float lo, float hi) {
    return bf16_rn(lo) | (bf16_rn(hi) << 16);
}
static __device__ __forceinline__ float bf_lo(unsigned v) { return __uint_as_float(v << 16); }
static __device__ __forceinline__ float bf_hi(unsigned v) { return __uint_as_float(v & 0xffff0000u); }

// ---------------- phase 1: hist + feature/weight cvt, one launch ----------------
__global__ __launch_bounds__(256) void prep(const int* __restrict__ c2a_dst,
                                            const int* __restrict__ a2c_dst, int E,
                                            int* __restrict__ cnt_a, int* __restrict__ bcnt,
                                            const float4* __restrict__ X4,
                                            uint2* __restrict__ xhi, uint2* __restrict__ xlo,
                                            const float* __restrict__ W,
                                            unsigned short* __restrict__ Wt) {
    int bid = blockIdx.x;
    if (bid < NHIST) {
        __shared__ int h[NAGG + NBKT];
        for (int i = threadIdx.x; i < NAGG + NBKT; i += 256) h[i] = 0;
        __syncthreads();
        int stride = NHIST * 256;
        for (int e = bid * 256 + threadIdx.x; e < E; e += stride) {
            atomicAdd(&h[c2a_dst[e]], 1);
            atomicAdd(&h[NAGG + (a2c_dst[e] >> 7)], 1);
        }
        __syncthreads();
        for (int i = threadIdx.x; i < NAGG; i += 256)
            if (h[i]) atomicAdd(&cnt_a[i], h[i]);
        for (int i = threadIdx.x; i < NBKT; i += 256)
            if (h[NAGG + i]) atomicAdd(&bcnt[i], h[NAGG + i]);
    } else if (bid < NHIST + NCVTX) {
        int t = (bid - NHIST) * 256 + threadIdx.x;
        float4 f = X4[t];
        unsigned h0 = bf16_rn(f.x), h1 = bf16_rn(f.y), h2 = bf16_rn(f.z), h3 = bf16_rn(f.w);
        xhi[t] = make_uint2(h0 | (h1 << 16), h2 | (h3 << 16));
        xlo[t] = make_uint2(pack_bf2(f.x - bf_val(h0), f.y - bf_val(h1)),
                            pack_bf2(f.z - bf_val(h2), f.w - bf_val(h3)));
    } else {
        int idx = (bid - NHIST - NCVTX) * 256 + threadIdx.x;
        if (idx >= NLAYER * D * D) return;
        int layer = idx >> 14, rem = idx & (D * D - 1);
        int k = rem >> 7, n = rem & 127;
        float w = W[layer * D * D + k * D + n];
        unsigned h = bf16_rn(w);
        unsigned short* base = Wt + layer * 2 * D * D;
        base[n * D + k] = (unsigned short)h;
        base[D * D + n * D + k] = (unsigned short)bf16_rn(w - bf_val(h));
    }
}

// ---------------- phase 2: scans ----------------
__global__ void scan_both(const int* __restrict__ cnt_a, int* __restrict__ rp_a,
                          int* __restrict__ cur_a, const int* __restrict__ bcnt,
                          int* __restrict__ brp, int* __restrict__ bcur) {
    __shared__ int sh[1024];
    const int* cnt;
    int *rp, *cur, n;
    if (blockIdx.x == 0) { cnt = cnt_a; rp = rp_a; cur = cur_a; n = NAGG; }
    else                 { cnt = bcnt;  rp = brp;  cur = bcur;  n = NBKT; }
    int t = threadIdx.x;
    int v = (t < n) ? cnt[t] : 0;
    sh[t] = v;
    __syncthreads();
    for (int off = 1; off < 1024; off <<= 1) {
        int x = (t >= off) ? sh[t - off] : 0;
        __syncthreads();
        sh[t] += x;
        __syncthreads();
    }
    if (t == 0) { rp[0] = 0; cur[0] = 0; }
    if (t < n) {
        rp[t + 1] = sh[t];
        if (t + 1 < n) cur[t + 1] = sh[t];
    }
}

// ---------------- phase 3: both scatters, one launch, 1024 threads ----------------
__global__ __launch_bounds__(1024) void scatter_both(const int* __restrict__ c2a_src,
                                                     const int* __restrict__ c2a_dst,
                                                     const int* __restrict__ a2c_src,
                                                     const int* __restrict__ a2c_dst, int E,
                                                     int* __restrict__ cur_a,
                                                     int* __restrict__ col_c2a,
                                                     int* __restrict__ bcur,
                                                     int* __restrict__ sorted1) {
    int tid = threadIdx.x;
    if (blockIdx.x < 256) {
        __shared__ int h[NAGG];
        __shared__ int base[NAGG];
        int chunk = (E + 255) / 256;
        int e0 = blockIdx.x * chunk;
        int e1 = min(E, e0 + chunk);
        for (int i = tid; i < NAGG; i += 1024) h[i] = 0;
        __syncthreads();
        for (int e = e0 + tid; e < e1; e += 1024) atomicAdd(&h[c2a_dst[e]], 1);
        __syncthreads();
        for (int i = tid; i < NAGG; i += 1024) {
            int c = h[i];
            base[i] = c ? atomicAdd(&cur_a[i], c) : 0;
        }
        __syncthreads();
        for (int e = e0 + tid; e < e1; e += 1024) {
            int pos = atomicAdd(&base[c2a_dst[e]], 1);
            col_c2a[pos] = c2a_src[e];
        }
    } else {
        __shared__ int h[NBKT];
        __shared__ int base[NBKT];
        int bid = blockIdx.x - 256;
        int chunk = (E + 255) / 256;
        int e0 = bid * chunk;
        int e1 = min(E, e0 + chunk);
        for (int i = tid; i < NBKT; i += 1024) h[i] = 0;
        __syncthreads();
        for (int e = e0 + tid; e < e1; e += 1024) atomicAdd(&h[a2c_dst[e] >> 7], 1);
        __syncthreads();
        for (int i = tid; i < NBKT; i += 1024) {
            int c = h[i];
            base[i] = c ? atomicAdd(&bcur[i], c) : 0;
        }
        __syncthreads();
        for (int e = e0 + tid; e < e1; e += 1024) {
            int d = a2c_dst[e];
            int pos = atomicAdd(&base[d >> 7], 1);
            sorted1[pos] = ((d & 127) << 10) | a2c_src[e];
        }
    }
}

// ---------------- phase 4: per-bucket client CSR ----------------
__global__ __launch_bounds__(512) void bucket_csr(const int* __restrict__ brp,
                                                  const int* __restrict__ sorted1,
                                                  int* __restrict__ rp_c,
                                                  int* __restrict__ col) {
    __shared__ int h[128], cur[128];
    int b = blockIdx.x, tid = threadIdx.x;
    if (tid < 128) h[tid] = 0;
    __syncthreads();
    int beg = brp[b], end = brp[b + 1];
    for (int e = beg + tid; e < end; e += 512) atomicAdd(&h[sorted1[e] >> 10], 1);
    __syncthreads();
    if (tid < 128) cur[tid] = h[tid];
    __syncthreads();
    for (int off = 1; off < 128; off <<= 1) {
        int x = 0;
        if (tid < 128 && tid >= off) x = cur[tid - off];
        __syncthreads();
        if (tid < 128) cur[tid] += x;
        __syncthreads();
    }
    if (tid < 128) {
        int start = beg + cur[tid] - h[tid];
        int c = b * 128 + tid;
        if (c < NCLI) rp_c[c] = start;
        cur[tid] = start;
    }
    if (b == NBKT - 1 && tid == 0) rp_c[NCLI] = end;
    __syncthreads();
    for (int e = beg + tid; e < end; e += 512) {
        int p = sorted1[e];
        int pos = atomicAdd(&cur[p >> 10], 1);
        col[pos] = p & 1023;
    }
}

// ---------------- layer kernels ----------------

// agg side: mean gather (uint4 wide: 16 lanes/row, 4 edges per wave-instr, 4-deep unroll)
// + ya = xa@Wl_a2c + xa_new = leaky(mean@Wl_c2a + xa@Wr_c2a + b). 512 threads.
__global__ __launch_bounds__(512) void agg_side(const unsigned* __restrict__ tbl,
                                                const int* __restrict__ rp_a,
                                                const int* __restrict__ col_c2a,
                                                const float* xa_old,
                                                const float* __restrict__ Wl_a2c,
                                                const float* __restrict__ Wl_c2a,
                                                const float* __restrict__ Wr_c2a,
                                                const float* __restrict__ b_c2a,
                                                unsigned short* __restrict__ ya_bf,
                                                float* xa_out) {
    __shared__ int cols[512];
    __shared__ float part[32][D];   // 16 KB partials, col-indexed
    __shared__ float mr[D], xr[D];
    int i = blockIdx.x, tid = threadIdx.x;
    int g = tid >> 6, lane = tid & 63;
    int sub = lane >> 4, sl = lane & 15;   // 16-lane row readers
    const uint4* tbl4 = (const uint4*)tbl;
    if (tid < D) xr[tid] = xa_old[i * D + tid];
    for (int k = tid; k < 32 * D; k += 512) ((float*)part)[k] = 0.f;
    __syncthreads();
    int beg = rp_a[i], end = rp_a[i + 1];
    float f0 = 0, f1 = 0, f2 = 0, f3 = 0, f4 = 0, f5 = 0, f6 = 0, f7 = 0;  // cols 8sl..8sl+7
    float t0 = 0, t1 = 0;                                                   // cols 2lane, 2lane+1
    for (int base = beg; base < end; base += 512) {
        int m = end - base;
        if (m > 512) m = 512;
        __syncthreads();
        if (tid < m) cols[tid] = col_c2a[base + tid];
        __syncthreads();
        int lo = g * 64;
        int hi_ = min(lo + 64, m);
        int t = lo;
        for (; t + 16 <= hi_; t += 16) {
            int e0 = cols[t + sub];
            int e1 = cols[t + 4 + sub];
            int e2 = cols[t + 8 + sub];
            int e3 = cols[t + 12 + sub];
            uint4 v0 = tbl4[(e0 << 4) + sl];
            uint4 v1 = tbl4[(e1 << 4) + sl];
            uint4 v2 = tbl4[(e2 << 4) + sl];
            uint4 v3 = tbl4[(e3 << 4) + sl];
            f0 += bf_lo(v0.x); f1 += bf_hi(v0.x); f2 += bf_lo(v0.y); f3 += bf_hi(v0.y);
            f4 += bf_lo(v0.z); f5 += bf_hi(v0.z); f6 += bf_lo(v0.w); f7 += bf_hi(v0.w);
            f0 += bf_lo(v1.x); f1 += bf_hi(v1.x); f2 += bf_lo(v1.y); f3 += bf_hi(v1.y);
            f4 += bf_lo(v1.z); f5 += bf_hi(v1.z); f6 += bf_lo(v1.w); f7 += bf_hi(v1.w);
            f0 += bf_lo(v2.x); f1 += bf_hi(v2.x); f2 += bf_lo(v2.y); f3 += bf_hi(v2.y);
            f4 += bf_lo(v2.z); f5 += bf_hi(v2.z); f6 += bf_lo(v2.w); f7 += bf_hi(v2.w);
            f0 += bf_lo(v3.x); f1 += bf_hi(v3.x); f2 += bf_lo(v3.y); f3 += bf_hi(v3.y);
            f4 += bf_lo(v3.z); f5 += bf_hi(v3.z); f6 += bf_lo(v3.w); f7 += bf_hi(v3.w);
        }
        for (; t < hi_; t++) {  // tail: whole 64-lane row read
            unsigned v = tbl[(cols[t] << 6) + lane];
            t0 += bf_lo(v); t1 += bf_hi(v);
        }
    }
    int r = g * 4 + sub;
    atomicAdd(&part[r][8 * sl + 0], f0); atomicAdd(&part[r][8 * sl + 1], f1);
    atomicAdd(&part[r][8 * sl + 2], f2); atomicAdd(&part[r][8 * sl + 3], f3);
    atomicAdd(&part[r][8 * sl + 4], f4); atomicAdd(&part[r][8 * sl + 5], f5);
    atomicAdd(&part[r][8 * sl + 6], f6); atomicAdd(&part[r][8 * sl + 7], f7);
    atomicAdd(&part[r][2 * lane], t0);   atomicAdd(&part[r][2 * lane + 1], t1);
    __syncthreads();
    if (tid < D) {
        float tot = 0.f;
#pragma unroll
        for (int gg = 0; gg < 32; gg++) tot += part[gg][tid];
        mr[tid] = tot / fmaxf((float)(end - beg), 1.f);
    }
    __syncthreads();
    if (tid < D) {
        int j = tid;
        float accy = 0.f, accn = b_c2a[j];
#pragma unroll 4
        for (int k = 0; k < D; k++) {
            accy += xr[k] * Wl_a2c[k * D + j];
            accn += mr[k] * Wl_c2a[k * D + j] + xr[k] * Wr_c2a[k * D + j];
        }
        ya_bf[i * D + j] = (unsigned short)bf16_rn(accy);
        xa_out[i * D + j] = leaky(accn);
    }
}

// Yb = (Ahi+Alo) @ (Whi+Wlo) + bias via 3 bf16 MFMA products. 4 waves, 64 rows. No LDS.
__global__ __launch_bounds__(256) void gemm_mfma(const unsigned short* __restrict__ Ahi,
                                                 const unsigned short* __restrict__ Alo,
                                                 const unsigned short* __restrict__ Wt,
                                                 const float* __restrict__ bias,
                                                 float* __restrict__ Y) {
    int tid = threadIdx.x;
    int wave = tid >> 6, lane = tid & 63;
    int t = lane & 15, q = lane >> 4;
    int m = blockIdx.x * 64 + wave * 16 + t;
    int mc = min(m, NCLI - 1);
    const unsigned short* arh = Ahi + (size_t)mc * D + q * 8;
    const unsigned short* arl = Alo + (size_t)mc * D + q * 8;
    bf16x8 ahi[4], alo[4];
#pragma unroll
    for (int kc = 0; kc < 4; kc++) {
        ahi[kc] = *(const bf16x8*)(arh + kc * 32);
        alo[kc] = *(const bf16x8*)(arl + kc * 32);
    }
    const unsigned short* Wlo = Wt + D * D;
    f32x4 acc[8];
#pragma unroll
    for (int nt = 0; nt < 8; nt++) {
        float bv = bias[nt * 16 + t];
        acc[nt] = (f32x4){bv, bv, bv, bv};
    }
#pragma unroll
    for (int nt = 0; nt < 8; nt++) {
        const unsigned short* brh = Wt + (size_t)(nt * 16 + t) * D + q * 8;
        const unsigned short* brl = Wlo + (size_t)(nt * 16 + t) * D + q * 8;
        bf16x8 bhi[4], blo[4];
#pragma unroll
        for (int kc = 0; kc < 4; kc++) {
            bhi[kc] = *(const bf16x8*)(brh + kc * 32);
            blo[kc] = *(const bf16x8*)(brl + kc * 32);
        }
#pragma unroll
        for (int kc = 0; kc < 4; kc++) {
            acc[nt] = __builtin_amdgcn_mfma_f32_16x16x32_bf16(ahi[kc], bhi[kc], acc[nt], 0, 0, 0);
            acc[nt] = __builtin_amdgcn_mfma_f32_16x16x32_bf16(alo[kc], bhi[kc], acc[nt], 0, 0, 0);
            acc[nt] = __builtin_amdgcn_mfma_f32_16x16x32_bf16(ahi[kc], blo[kc], acc[nt], 0, 0, 0);
        }
    }
    int row0 = blockIdx.x * 64 + wave * 16 + q * 4;
#pragma unroll
    for (int reg = 0; reg < 4; reg++) {
        int row = row0 + reg;
        if (row < NCLI) {
            float* yr = Y + (size_t)row * D + t;
#pragma unroll
            for (int nt = 0; nt < 8; nt++) yr[nt * 16] = acc[nt][reg];
        }
    }
}

// xc = leaky(Yb + mean_e ya[col[e]]). One wave/client; uint2 wide gather: 32 lanes/row,
// 2 edges per wave-instr, 8-deep unroll (16 edges in flight). shfl_xor(32) half-combine.
template <int LAST>
__global__ __launch_bounds__(256) void agg_c_bf(const unsigned* __restrict__ ya,
                                                const int* __restrict__ rowptr,
                                                const int* __restrict__ col,
                                                const float* __restrict__ Y,
                                                unsigned* __restrict__ xhi,
                                                unsigned* __restrict__ xlo,
                                                const float* __restrict__ Wlin,
                                                const float* __restrict__ blin,
                                                float* __restrict__ out, int E) {
    int lane = threadIdx.x & 63;
    int gid = blockIdx.x * 4 + (threadIdx.x >> 6);
    if (gid >= NCLI) return;
    int sub = lane >> 5, sl = lane & 31;   // 32-lane row readers; cols 4sl..4sl+3
    const uint2* ya2 = (const uint2*)ya;
    int beg = rowptr[gid], end = rowptr[gid + 1];
    float a0 = 0, a1 = 0, a2 = 0, a3 = 0;   // even unroll slots
    float b0 = 0, b1 = 0, b2 = 0, b3 = 0;   // odd unroll slots
    for (int ch = beg; ch < end; ch += 64) {
        int len = min(64, end - ch);
        int ec = col[min(ch + lane, E - 1)];
        int j = 0;
        for (; j + 16 <= len; j += 16) {
            int e0 = __shfl(ec, j + 0 + sub),  e1 = __shfl(ec, j + 2 + sub);
            int e2 = __shfl(ec, j + 4 + sub),  e3 = __shfl(ec, j + 6 + sub);
            int e4 = __shfl(ec, j + 8 + sub),  e5 = __shfl(ec, j + 10 + sub);
            int e6 = __shfl(ec, j + 12 + sub), e7 = __shfl(ec, j + 14 + sub);
            uint2 v0 = ya2[(e0 << 5) + sl];
            uint2 v1 = ya2[(e1 << 5) + sl];
            uint2 v2 = ya2[(e2 << 5) + sl];
            uint2 v3 = ya2[(e3 << 5) + sl];
            uint2 v4 = ya2[(e4 << 5) + sl];
            uint2 v5 = ya2[(e5 << 5) + sl];
            uint2 v6 = ya2[(e6 << 5) + sl];
            uint2 v7 = ya2[(e7 << 5) + sl];
            a0 += bf_lo(v0.x); a1 += bf_hi(v0.x); a2 += bf_lo(v0.y); a3 += bf_hi(v0.y);
            b0 += bf_lo(v1.x); b1 += bf_hi(v1.x); b2 += bf_lo(v1.y); b3 += bf_hi(v1.y);
            a0 += bf_lo(v2.x); a1 += bf_hi(v2.x); a2 += bf_lo(v2.y); a3 += bf_hi(v2.y);
            b0 += bf_lo(v3.x); b1 += bf_hi(v3.x); b2 += bf_lo(v3.y); b3 += bf_hi(v3.y);
            a0 += bf_lo(v4.x); a1 += bf_hi(v4.x); a2 += bf_lo(v4.y); a3 += bf_hi(v4.y);
            b0 += bf_lo(v5.x); b1 += bf_hi(v5.x); b2 += bf_lo(v5.y); b3 += bf_hi(v5.y);
            a0 += bf_lo(v6.x); a1 += bf_hi(v6.x); a2 += bf_lo(v6.y); a3 += bf_hi(v6.y);
            b0 += bf_lo(v7.x); b1 += bf_hi(v7.x); b2 += bf_lo(v7.y); b3 += bf_hi(v7.y);
        }
        for (; j + 2 <= len; j += 2) {
            int e = __shfl(ec, j + sub);
            uint2 v = ya2[(e << 5) + sl];
            a0 += bf_lo(v.x); a1 += bf_hi(v.x); a2 += bf_lo(v.y); a3 += bf_hi(v.y);
        }
        if (j < len) {
            int e = __shfl(ec, j);
            if (sub == 0) {
                uint2 v = ya2[(e << 5) + sl];
                a0 += bf_lo(v.x); a1 += bf_hi(v.x); a2 += bf_lo(v.y); a3 += bf_hi(v.y);
            }
        }
    }
    a0 += b0; a1 += b1; a2 += b2; a3 += b3;
    a0 += __shfl_xor(a0, 32); a1 += __shfl_xor(a1, 32);
    a2 += __shfl_xor(a2, 32); a3 += __shfl_xor(a3, 32);
    float inv = 1.f / fmaxf((float)(end - beg), 1.f);
    if (LAST) {
        float v = 0.f;
        if (sub == 0) {
            float4 yv = *(const float4*)&Y[(size_t)gid * D + 4 * sl];
            float4 w = *(const float4*)&Wlin[4 * sl];
            float r0 = leaky(yv.x + a0 * inv);
            float r1 = leaky(yv.y + a1 * inv);
            float r2 = leaky(yv.z + a2 * inv);
            float r3 = leaky(yv.w + a3 * inv);
            v = r0 * w.x + r1 * w.y + r2 * w.z + r3 * w.w;
        }
#pragma unroll
        for (int off = 32; off > 0; off >>= 1) v += __shfl_down(v, off);
        if (lane == 0) out[gid] = v + blin[0];
    } else {
        if (sub == 0) {
            float4 yv = *(const float4*)&Y[(size_t)gid * D + 4 * sl];
            float r0 = leaky(yv.x + a0 * inv);
            float r1 = leaky(yv.y + a1 * inv);
            float r2 = leaky(yv.z + a2 * inv);
            float r3 = leaky(yv.w + a3 * inv);
            unsigned h0 = bf16_rn(r0), h1 = bf16_rn(r1), h2 = bf16_rn(r2), h3 = bf16_rn(r3);
            ((uint2*)xhi)[(gid << 5) + sl] = make_uint2(h0 | (h1 << 16), h2 | (h3 << 16));
            ((uint2*)xlo)[(gid << 5) + sl] =
                make_uint2(pack_bf2(r0 - bf_val(h0), r1 - bf_val(h1)),
                           pack_bf2(r2 - bf_val(h2), r3 - bf_val(h3)));
        }
    }
}

extern "C" void kernel_launch(void* const* d_in, const int* in_sizes, int n_in,
                              void* d_out, int out_size, void* d_ws, size_t ws_size,
                              hipStream_t stream) {
    const float* x_clients = (const float*)d_in[0];
    const float* x_agg     = (const float*)d_in[1];
    const int*   c2a_src   = (const int*)d_in[2];
    const int*   c2a_dst   = (const int*)d_in[3];
    const int*   a2c_src   = (const int*)d_in[4];
    const int*   a2c_dst   = (const int*)d_in[5];
    const float* Wl_c2a    = (const float*)d_in[6];
    const float* Wr_c2a    = (const float*)d_in[7];
    const float* b_c2a     = (const float*)d_in[8];
    const float* Wl_a2c    = (const float*)d_in[9];
    const float* Wr_a2c    = (const float*)d_in[10];
    const float* b_a2c     = (const float*)d_in[11];
    const float* W_lin     = (const float*)d_in[12];
    const float* b_lin     = (const float*)d_in[13];
    float* out = (float*)d_out;
    const int E = in_sizes[2];

    char* p = (char*)d_ws;
    auto alloc = [&](size_t bytes) {
        char* r = p;
        p += (bytes + 255) & ~(size_t)255;
        return r;
    };
    float*    Yb    = (float*)alloc(sizeof(float) * NCLI * D);         // gemm output (f32)
    unsigned* xc_hi = (unsigned*)alloc(sizeof(unsigned) * NCLI * 64);  // bf16 hi (also gather tbl)
    unsigned* xc_lo = (unsigned*)alloc(sizeof(unsigned) * NCLI * 64);  // bf16 lo
    float*    xa    = (float*)alloc(sizeof(float) * NAGG * D);
    unsigned short* ya_bf = (unsigned short*)alloc(sizeof(unsigned short) * NAGG * D);
    unsigned short* Wt = (unsigned short*)alloc(sizeof(unsigned short) * NLAYER * 2 * D * D);
    int* cnt_a = (int*)alloc(sizeof(int) * 2048);  // cnt_a[0..1023] + bcnt[1024..]
    int* bcnt  = cnt_a + 1024;
    int* rp_a  = (int*)alloc(sizeof(int) * (NAGG + 1));
    int* cur_a = (int*)alloc(sizeof(int) * NAGG);
    int* brp   = (int*)alloc(sizeof(int) * (NBKT + 1));
    int* bcur  = (int*)alloc(sizeof(int) * NBKT);
    int* rp_c  = (int*)alloc(sizeof(int) * (NCLI + 1));
    int* col_c2a = (int*)alloc(sizeof(int) * E);
    int* col_a2c = (int*)alloc(sizeof(int) * E);
    // sorted1 aliases Yb: lifetime disjoint (CSR build completes before layer-0 gemm writes Yb)
    int* sorted1 = (int*)Yb;

    hipMemsetAsync(cnt_a, 0, sizeof(int) * 2048, stream);

    prep<<<NHIST + NCVTX + NCVTW, 256, 0, stream>>>(c2a_dst, a2c_dst, E, cnt_a, bcnt,
                                                    (const float4*)x_clients,
                                                    (uint2*)xc_hi, (uint2*)xc_lo,
                                                    Wr_a2c, Wt);
    scan_both<<<2, 1024, 0, stream>>>(cnt_a, rp_a, cur_a, bcnt, brp, bcur);
    scatter_both<<<512, 1024, 0, stream>>>(c2a_src, c2a_dst, a2c_src, a2c_dst, E,
                                           cur_a, col_c2a, bcur, sorted1);
    bucket_csr<<<NBKT, 512, 0, stream>>>(brp, sorted1, rp_c, col_a2c);

    const float* xa_old = x_agg;
    for (int l = 0; l < NLAYER; l++) {
        agg_side<<<NAGG, 512, 0, stream>>>(xc_hi, rp_a, col_c2a, xa_old,
                                           Wl_a2c + l * D * D, Wl_c2a + l * D * D,
                                           Wr_c2a + l * D * D, b_c2a + l * D, ya_bf, xa);
        gemm_mfma<<<(NCLI + 63) / 64, 256, 0, stream>>>(
            (const unsigned short*)xc_hi, (const unsigned short*)xc_lo,
            Wt + l * 2 * D * D, b_a2c + l * D, Yb);
        if (l < NLAYER - 1) {
            agg_c_bf<0><<<(NCLI + 3) / 4, 256, 0, stream>>>((const unsigned*)ya_bf, rp_c, col_a2c,
                                                            Yb, xc_hi, xc_lo, nullptr, nullptr,
                                                            nullptr, E);
        } else {
            agg_c_bf<1><<<(NCLI + 3) / 4, 256, 0, stream>>>((const unsigned*)ya_bf, rp_c, col_a2c,
                                                            Yb, nullptr, nullptr, W_lin, b_lin,
                                                            out, E);
        }
        xa_old = xa;
    }
}

// Round 10
// 697.674 us; speedup vs baseline: 1.1182x; 1.1182x over previous
//
#include <hip/hip_runtime.h>

#define D      128
#define NCLI   100000
#define NAGG   1000
#define NLAYER 3
#define NBKT   782   // ceil(NCLI/128)
#define NHIST  512
#define NCVTX  (NCLI * D / 4 / 256)   // 12500
#define NCVTW  ((NLAYER * D * D + 255) / 256)  // 192
#define NROWT  (NCLI / 32)            // 3125 row-tiles (exact)

typedef short bf16x8 __attribute__((ext_vector_type(8)));
typedef float f32x16 __attribute__((ext_vector_type(16)));

static __device__ __forceinline__ float leaky(float x) { return x >= 0.f ? x : 0.1f * x; }

// ---- bf16 pack/unpack (RNE) ----
static __device__ __forceinline__ unsigned bf16_rn(float f) {
    unsigned u = __float_as_uint(f);
    return (u + 0x7fffu + ((u >> 16) & 1u)) >> 16;
}
static __device__ __forceinline__ float bf_val(unsigned h) { return __uint_as_float(h << 16); }
static __device__ __forceinline__ unsigned pack_bf2(float lo, float hi) {
    return bf16_rn(lo) | (bf16_rn(hi) << 16);
}
static __device__ __forceinline__ float bf_lo(unsigned v) { return __uint_as_float(v << 16); }
static __device__ __forceinline__ float bf_hi(unsigned v) { return __uint_as_float(v & 0xffff0000u); }

// ---------------- phase 1: hist + feature/weight cvt, one launch ----------------
__global__ __launch_bounds__(256) void prep(const int* __restrict__ c2a_dst,
                                            const int* __restrict__ a2c_dst, int E,
                                            int* __restrict__ cnt_a, int* __restrict__ bcnt,
                                            const float4* __restrict__ X4,
                                            uint2* __restrict__ xhi, uint2* __restrict__ xlo,
                                            const float* __restrict__ W,
                                            unsigned short* __restrict__ Wt) {
    int bid = blockIdx.x;
    if (bid < NHIST) {
        __shared__ int h[NAGG + NBKT];
        for (int i = threadIdx.x; i < NAGG + NBKT; i += 256) h[i] = 0;
        __syncthreads();
        int stride = NHIST * 256;
        for (int e = bid * 256 + threadIdx.x; e < E; e += stride) {
            atomicAdd(&h[c2a_dst[e]], 1);
            atomicAdd(&h[NAGG + (a2c_dst[e] >> 7)], 1);
        }
        __syncthreads();
        for (int i = threadIdx.x; i < NAGG; i += 256)
            if (h[i]) atomicAdd(&cnt_a[i], h[i]);
        for (int i = threadIdx.x; i < NBKT; i += 256)
            if (h[NAGG + i]) atomicAdd(&bcnt[i], h[NAGG + i]);
    } else if (bid < NHIST + NCVTX) {
        int t = (bid - NHIST) * 256 + threadIdx.x;
        float4 f = X4[t];
        unsigned h0 = bf16_rn(f.x), h1 = bf16_rn(f.y), h2 = bf16_rn(f.z), h3 = bf16_rn(f.w);
        xhi[t] = make_uint2(h0 | (h1 << 16), h2 | (h3 << 16));
        xlo[t] = make_uint2(pack_bf2(f.x - bf_val(h0), f.y - bf_val(h1)),
                            pack_bf2(f.z - bf_val(h2), f.w - bf_val(h3)));
    } else {
        int idx = (bid - NHIST - NCVTX) * 256 + threadIdx.x;
        if (idx >= NLAYER * D * D) return;
        int layer = idx >> 14, rem = idx & (D * D - 1);
        int k = rem >> 7, n = rem & 127;
        float w = W[layer * D * D + k * D + n];
        unsigned h = bf16_rn(w);
        unsigned short* base = Wt + layer * 2 * D * D;
        base[n * D + k] = (unsigned short)h;
        base[D * D + n * D + k] = (unsigned short)bf16_rn(w - bf_val(h));
    }
}

// ---------------- phase 2: scans ----------------
__global__ void scan_both(const int* __restrict__ cnt_a, int* __restrict__ rp_a,
                          int* __restrict__ cur_a, const int* __restrict__ bcnt,
                          int* __restrict__ brp, int* __restrict__ bcur) {
    __shared__ int sh[1024];
    const int* cnt;
    int *rp, *cur, n;
    if (blockIdx.x == 0) { cnt = cnt_a; rp = rp_a; cur = cur_a; n = NAGG; }
    else                 { cnt = bcnt;  rp = brp;  cur = bcur;  n = NBKT; }
    int t = threadIdx.x;
    int v = (t < n) ? cnt[t] : 0;
    sh[t] = v;
    __syncthreads();
    for (int off = 1; off < 1024; off <<= 1) {
        int x = (t >= off) ? sh[t - off] : 0;
        __syncthreads();
        sh[t] += x;
        __syncthreads();
    }
    if (t == 0) { rp[0] = 0; cur[0] = 0; }
    if (t < n) {
        rp[t + 1] = sh[t];
        if (t + 1 < n) cur[t + 1] = sh[t];
    }
}

// ---------------- phase 3: both scatters, one launch, 1024 threads ----------------
__global__ __launch_bounds__(1024) void scatter_both(const int* __restrict__ c2a_src,
                                                     const int* __restrict__ c2a_dst,
                                                     const int* __restrict__ a2c_src,
                                                     const int* __restrict__ a2c_dst, int E,
                                                     int* __restrict__ cur_a,
                                                     int* __restrict__ col_c2a,
                                                     int* __restrict__ bcur,
                                                     int* __restrict__ sorted1) {
    int tid = threadIdx.x;
    if (blockIdx.x < 256) {
        __shared__ int h[NAGG];
        __shared__ int base[NAGG];
        int chunk = (E + 255) / 256;
        int e0 = blockIdx.x * chunk;
        int e1 = min(E, e0 + chunk);
        for (int i = tid; i < NAGG; i += 1024) h[i] = 0;
        __syncthreads();
        for (int e = e0 + tid; e < e1; e += 1024) atomicAdd(&h[c2a_dst[e]], 1);
        __syncthreads();
        for (int i = tid; i < NAGG; i += 1024) {
            int c = h[i];
            base[i] = c ? atomicAdd(&cur_a[i], c) : 0;
        }
        __syncthreads();
        for (int e = e0 + tid; e < e1; e += 1024) {
            int pos = atomicAdd(&base[c2a_dst[e]], 1);
            col_c2a[pos] = c2a_src[e];
        }
    } else {
        __shared__ int h[NBKT];
        __shared__ int base[NBKT];
        int bid = blockIdx.x - 256;
        int chunk = (E + 255) / 256;
        int e0 = bid * chunk;
        int e1 = min(E, e0 + chunk);
        for (int i = tid; i < NBKT; i += 1024) h[i] = 0;
        __syncthreads();
        for (int e = e0 + tid; e < e1; e += 1024) atomicAdd(&h[a2c_dst[e] >> 7], 1);
        __syncthreads();
        for (int i = tid; i < NBKT; i += 1024) {
            int c = h[i];
            base[i] = c ? atomicAdd(&bcur[i], c) : 0;
        }
        __syncthreads();
        for (int e = e0 + tid; e < e1; e += 1024) {
            int d = a2c_dst[e];
            int pos = atomicAdd(&base[d >> 7], 1);
            sorted1[pos] = ((d & 127) << 10) | a2c_src[e];
        }
    }
}

// ---------------- phase 4: per-bucket client CSR ----------------
__global__ __launch_bounds__(512) void bucket_csr(const int* __restrict__ brp,
                                                  const int* __restrict__ sorted1,
                                                  int* __restrict__ rp_c,
                                                  int* __restrict__ col) {
    __shared__ int h[128], cur[128];
    int b = blockIdx.x, tid = threadIdx.x;
    if (tid < 128) h[tid] = 0;
    __syncthreads();
    int beg = brp[b], end = brp[b + 1];
    for (int e = beg + tid; e < end; e += 512) atomicAdd(&h[sorted1[e] >> 10], 1);
    __syncthreads();
    if (tid < 128) cur[tid] = h[tid];
    __syncthreads();
    for (int off = 1; off < 128; off <<= 1) {
        int x = 0;
        if (tid < 128 && tid >= off) x = cur[tid - off];
        __syncthreads();
        if (tid < 128) cur[tid] += x;
        __syncthreads();
    }
    if (tid < 128) {
        int start = beg + cur[tid] - h[tid];
        int c = b * 128 + tid;
        if (c < NCLI) rp_c[c] = start;
        cur[tid] = start;
    }
    if (b == NBKT - 1 && tid == 0) rp_c[NCLI] = end;
    __syncthreads();
    for (int e = beg + tid; e < end; e += 512) {
        int p = sorted1[e];
        int pos = atomicAdd(&cur[p >> 10], 1);
        col[pos] = p & 1023;
    }
}

// ---------------- layer kernels ----------------

// agg side (R8-measured 78 µs version): uint4 wide mean gather + ya + xa update.
__global__ __launch_bounds__(512) void agg_side(const unsigned* __restrict__ tbl,
                                                const int* __restrict__ rp_a,
                                                const int* __restrict__ col_c2a,
                                                const float* xa_old,
                                                const float* __restrict__ Wl_a2c,
                                                const float* __restrict__ Wl_c2a,
                                                const float* __restrict__ Wr_c2a,
                                                const float* __restrict__ b_c2a,
                                                unsigned short* __restrict__ ya_bf,
                                                float* xa_out) {
    __shared__ int cols[512];
    __shared__ float part[32][D];
    __shared__ float mr[D], xr[D];
    int i = blockIdx.x, tid = threadIdx.x;
    int g = tid >> 6, lane = tid & 63;
    int sub = lane >> 4, sl = lane & 15;
    const uint4* tbl4 = (const uint4*)tbl;
    if (tid < D) xr[tid] = xa_old[i * D + tid];
    for (int k = tid; k < 32 * D; k += 512) ((float*)part)[k] = 0.f;
    __syncthreads();
    int beg = rp_a[i], end = rp_a[i + 1];
    float f0 = 0, f1 = 0, f2 = 0, f3 = 0, f4 = 0, f5 = 0, f6 = 0, f7 = 0;
    float t0 = 0, t1 = 0;
    for (int base = beg; base < end; base += 512) {
        int m = end - base;
        if (m > 512) m = 512;
        __syncthreads();
        if (tid < m) cols[tid] = col_c2a[base + tid];
        __syncthreads();
        int lo = g * 64;
        int hi_ = min(lo + 64, m);
        int t = lo;
        for (; t + 16 <= hi_; t += 16) {
            int e0 = cols[t + sub];
            int e1 = cols[t + 4 + sub];
            int e2 = cols[t + 8 + sub];
            int e3 = cols[t + 12 + sub];
            uint4 v0 = tbl4[(e0 << 4) + sl];
            uint4 v1 = tbl4[(e1 << 4) + sl];
            uint4 v2 = tbl4[(e2 << 4) + sl];
            uint4 v3 = tbl4[(e3 << 4) + sl];
            f0 += bf_lo(v0.x); f1 += bf_hi(v0.x); f2 += bf_lo(v0.y); f3 += bf_hi(v0.y);
            f4 += bf_lo(v0.z); f5 += bf_hi(v0.z); f6 += bf_lo(v0.w); f7 += bf_hi(v0.w);
            f0 += bf_lo(v1.x); f1 += bf_hi(v1.x); f2 += bf_lo(v1.y); f3 += bf_hi(v1.y);
            f4 += bf_lo(v1.z); f5 += bf_hi(v1.z); f6 += bf_lo(v1.w); f7 += bf_hi(v1.w);
            f0 += bf_lo(v2.x); f1 += bf_hi(v2.x); f2 += bf_lo(v2.y); f3 += bf_hi(v2.y);
            f4 += bf_lo(v2.z); f5 += bf_hi(v2.z); f6 += bf_lo(v2.w); f7 += bf_hi(v2.w);
            f0 += bf_lo(v3.x); f1 += bf_hi(v3.x); f2 += bf_lo(v3.y); f3 += bf_hi(v3.y);
            f4 += bf_lo(v3.z); f5 += bf_hi(v3.z); f6 += bf_lo(v3.w); f7 += bf_hi(v3.w);
        }
        for (; t < hi_; t++) {
            unsigned v = tbl[(cols[t] << 6) + lane];
            t0 += bf_lo(v); t1 += bf_hi(v);
        }
    }
    int r = g * 4 + sub;
    atomicAdd(&part[r][8 * sl + 0], f0); atomicAdd(&part[r][8 * sl + 1], f1);
    atomicAdd(&part[r][8 * sl + 2], f2); atomicAdd(&part[r][8 * sl + 3], f3);
    atomicAdd(&part[r][8 * sl + 4], f4); atomicAdd(&part[r][8 * sl + 5], f5);
    atomicAdd(&part[r][8 * sl + 6], f6); atomicAdd(&part[r][8 * sl + 7], f7);
    atomicAdd(&part[r][2 * lane], t0);   atomicAdd(&part[r][2 * lane + 1], t1);
    __syncthreads();
    if (tid < D) {
        float tot = 0.f;
#pragma unroll
        for (int gg = 0; gg < 32; gg++) tot += part[gg][tid];
        mr[tid] = tot / fmaxf((float)(end - beg), 1.f);
    }
    __syncthreads();
    if (tid < D) {
        int j = tid;
        float accy = 0.f, accn = b_c2a[j];
#pragma unroll 4
        for (int k = 0; k < D; k++) {
            accy += xr[k] * Wl_a2c[k * D + j];
            accn += mr[k] * Wl_c2a[k * D + j] + xr[k] * Wr_c2a[k * D + j];
        }
        ya_bf[i * D + j] = (unsigned short)bf16_rn(accy);
        xa_out[i * D + j] = leaky(accn);
    }
}

// Persistent split-bf16 MFMA gemm, 32x32x16 shape (2x arithmetic intensity).
// 4 waves/block; wave w owns col-tile n0=w*32 with its B hi/lo fragments held in
// REGISTERS across all row-tiles (B loaded once per wave, not once per row-tile).
// Grid-stride over 3125 row-tiles of 32 rows. NCLI = 3125*32 exactly -> no clamps.
// A frag: m=lane&31, k=(lane>>5)*8+j.  C/D: col=lane&31, row=(reg&3)+8*(reg>>2)+4*(lane>>5).
__global__ __launch_bounds__(256) void gemm_mfma(const unsigned short* __restrict__ Ahi,
                                                 const unsigned short* __restrict__ Alo,
                                                 const unsigned short* __restrict__ Wt,
                                                 const float* __restrict__ bias,
                                                 float* __restrict__ Y) {
    int tid = threadIdx.x;
    int wave = tid >> 6, lane = tid & 63;
    int cl = lane & 31, kh = lane >> 5;
    int n0 = wave * 32;
    const unsigned short* Wlo = Wt + D * D;
    const unsigned short* wbh = Wt + (size_t)(n0 + cl) * D + kh * 8;
    const unsigned short* wbl = Wlo + (size_t)(n0 + cl) * D + kh * 8;
    bf16x8 bhi[8], blo[8];
#pragma unroll
    for (int kc = 0; kc < 8; kc++) {
        bhi[kc] = *(const bf16x8*)(wbh + kc * 16);
        blo[kc] = *(const bf16x8*)(wbl + kc * 16);
    }
    float bv = bias[n0 + cl];
    for (int r = blockIdx.x; r < NROWT; r += gridDim.x) {
        int m0 = r * 32;
        const unsigned short* ar = Ahi + (size_t)(m0 + cl) * D + kh * 8;
        const unsigned short* al = Alo + (size_t)(m0 + cl) * D + kh * 8;
        bf16x8 ahi[8], alo[8];
#pragma unroll
        for (int kc = 0; kc < 8; kc++) {
            ahi[kc] = *(const bf16x8*)(ar + kc * 16);
            alo[kc] = *(const bf16x8*)(al + kc * 16);
        }
        f32x16 acc;
#pragma unroll
        for (int q = 0; q < 16; q++) acc[q] = bv;
#pragma unroll
        for (int kc = 0; kc < 8; kc++) {
            acc = __builtin_amdgcn_mfma_f32_32x32x16_bf16(ahi[kc], bhi[kc], acc, 0, 0, 0);
            acc = __builtin_amdgcn_mfma_f32_32x32x16_bf16(alo[kc], bhi[kc], acc, 0, 0, 0);
            acc = __builtin_amdgcn_mfma_f32_32x32x16_bf16(ahi[kc], blo[kc], acc, 0, 0, 0);
        }
        float* yb = Y + (size_t)m0 * D + n0 + cl;
#pragma unroll
        for (int reg = 0; reg < 16; reg++) {
            int row = (reg & 3) + 8 * (reg >> 2) + 4 * kh;
            yb[(size_t)row * D] = acc[reg];
        }
    }
}

// xc = leaky(Yb + mean_e ya_bf[col[e]]) — R7-proven scalar version.
// One wave per client; col indices coalesced-loaded then shfl-broadcast; 8 gathers in flight.
template <int LAST>
__global__ __launch_bounds__(256) void agg_c_bf(const unsigned* __restrict__ ya,
                                                const int* __restrict__ rowptr,
                                                const int* __restrict__ col,
                                                const float* __restrict__ Y,
                                                unsigned* __restrict__ xhi,
                                                unsigned* __restrict__ xlo,
                                                const float* __restrict__ Wlin,
                                                const float* __restrict__ blin,
                                                float* __restrict__ out, int E) {
    int l = threadIdx.x & 63;
    int gid = blockIdx.x * 4 + (threadIdx.x >> 6);
    if (gid >= NCLI) return;
    int beg = rowptr[gid], end = rowptr[gid + 1];
    float a0 = 0, b0 = 0, a1 = 0, b1 = 0, a2 = 0, b2 = 0, a3 = 0, b3 = 0;
    float a4 = 0, b4 = 0, a5 = 0, b5 = 0, a6 = 0, b6 = 0, a7 = 0, b7 = 0;
    for (int ch = beg; ch < end; ch += 64) {
        int len = min(64, end - ch);
        int ec = col[min(ch + l, E - 1)];
        int j = 0;
        for (; j + 8 <= len; j += 8) {
            int r0 = __shfl(ec, j + 0), r1 = __shfl(ec, j + 1);
            int r2 = __shfl(ec, j + 2), r3 = __shfl(ec, j + 3);
            int r4 = __shfl(ec, j + 4), r5 = __shfl(ec, j + 5);
            int r6 = __shfl(ec, j + 6), r7 = __shfl(ec, j + 7);
            unsigned v0 = ya[(r0 << 6) + l];
            unsigned v1 = ya[(r1 << 6) + l];
            unsigned v2 = ya[(r2 << 6) + l];
            unsigned v3 = ya[(r3 << 6) + l];
            unsigned v4 = ya[(r4 << 6) + l];
            unsigned v5 = ya[(r5 << 6) + l];
            unsigned v6 = ya[(r6 << 6) + l];
            unsigned v7 = ya[(r7 << 6) + l];
            a0 += bf_lo(v0); b0 += bf_hi(v0);
            a1 += bf_lo(v1); b1 += bf_hi(v1);
            a2 += bf_lo(v2); b2 += bf_hi(v2);
            a3 += bf_lo(v3); b3 += bf_hi(v3);
            a4 += bf_lo(v4); b4 += bf_hi(v4);
            a5 += bf_lo(v5); b5 += bf_hi(v5);
            a6 += bf_lo(v6); b6 += bf_hi(v6);
            a7 += bf_lo(v7); b7 += bf_hi(v7);
        }
        for (; j < len; j++) {
            int r = __shfl(ec, j);
            unsigned v = ya[(r << 6) + l];
            a0 += bf_lo(v); b0 += bf_hi(v);
        }
    }
    float sx = ((a0 + a1) + (a2 + a3)) + ((a4 + a5) + (a6 + a7));
    float sy = ((b0 + b1) + (b2 + b3)) + ((b4 + b5) + (b6 + b7));
    float inv = 1.f / fmaxf((float)(end - beg), 1.f);
    float2 yv = *(const float2*)&Y[(size_t)gid * D + 2 * l];
    float r0 = leaky(yv.x + sx * inv);
    float r1 = leaky(yv.y + sy * inv);
    if (LAST) {
        float2 w = *(const float2*)&Wlin[2 * l];
        float v = r0 * w.x + r1 * w.y;
#pragma unroll
        for (int off = 32; off > 0; off >>= 1) v += __shfl_down(v, off);
        if (l == 0) out[gid] = v + blin[0];
    } else {
        unsigned h0 = bf16_rn(r0), h1 = bf16_rn(r1);
        xhi[(gid << 6) + l] = h0 | (h1 << 16);
        xlo[(gid << 6) + l] = pack_bf2(r0 - bf_val(h0), r1 - bf_val(h1));
    }
}

extern "C" void kernel_launch(void* const* d_in, const int* in_sizes, int n_in,
                              void* d_out, int out_size, void* d_ws, size_t ws_size,
                              hipStream_t stream) {
    const float* x_clients = (const float*)d_in[0];
    const float* x_agg     = (const float*)d_in[1];
    const int*   c2a_src   = (const int*)d_in[2];
    const int*   c2a_dst   = (const int*)d_in[3];
    const int*   a2c_src   = (const int*)d_in[4];
    const int*   a2c_dst   = (const int*)d_in[5];
    const float* Wl_c2a    = (const float*)d_in[6];
    const float* Wr_c2a    = (const float*)d_in[7];
    const float* b_c2a     = (const float*)d_in[8];
    const float* Wl_a2c    = (const float*)d_in[9];
    const float* Wr_a2c    = (const float*)d_in[10];
    const float* b_a2c     = (const float*)d_in[11];
    const float* W_lin     = (const float*)d_in[12];
    const float* b_lin     = (const float*)d_in[13];
    float* out = (float*)d_out;
    const int E = in_sizes[2];

    char* p = (char*)d_ws;
    auto alloc = [&](size_t bytes) {
        char* r = p;
        p += (bytes + 255) & ~(size_t)255;
        return r;
    };
    float*    Yb    = (float*)alloc(sizeof(float) * NCLI * D);         // gemm output (f32)
    unsigned* xc_hi = (unsigned*)alloc(sizeof(unsigned) * NCLI * 64);  // bf16 hi (also gather tbl)
    unsigned* xc_lo = (unsigned*)alloc(sizeof(unsigned) * NCLI * 64);  // bf16 lo
    float*    xa    = (float*)alloc(sizeof(float) * NAGG * D);
    unsigned short* ya_bf = (unsigned short*)alloc(sizeof(unsigned short) * NAGG * D);
    unsigned short* Wt = (unsigned short*)alloc(sizeof(unsigned short) * NLAYER * 2 * D * D);
    int* cnt_a = (int*)alloc(sizeof(int) * 2048);  // cnt_a[0..1023] + bcnt[1024..]
    int* bcnt  = cnt_a + 1024;
    int* rp_a  = (int*)alloc(sizeof(int) * (NAGG + 1));
    int* cur_a = (int*)alloc(sizeof(int) * NAGG);
    int* brp   = (int*)alloc(sizeof(int) * (NBKT + 1));
    int* bcur  = (int*)alloc(sizeof(int) * NBKT);
    int* rp_c  = (int*)alloc(sizeof(int) * (NCLI + 1));
    int* col_c2a = (int*)alloc(sizeof(int) * E);
    int* col_a2c = (int*)alloc(sizeof(int) * E);
    // sorted1 aliases Yb: lifetime disjoint (CSR build completes before layer-0 gemm writes Yb)
    int* sorted1 = (int*)Yb;

    hipMemsetAsync(cnt_a, 0, sizeof(int) * 2048, stream);

    prep<<<NHIST + NCVTX + NCVTW, 256, 0, stream>>>(c2a_dst, a2c_dst, E, cnt_a, bcnt,
                                                    (const float4*)x_clients,
                                                    (uint2*)xc_hi, (uint2*)xc_lo,
                                                    Wr_a2c, Wt);
    scan_both<<<2, 1024, 0, stream>>>(cnt_a, rp_a, cur_a, bcnt, brp, bcur);
    scatter_both<<<512, 1024, 0, stream>>>(c2a_src, c2a_dst, a2c_src, a2c_dst, E,
                                           cur_a, col_c2a, bcur, sorted1);
    bucket_csr<<<NBKT, 512, 0, stream>>>(brp, sorted1, rp_c, col_a2c);

    const float* xa_old = x_agg;
    for (int l = 0; l < NLAYER; l++) {
        agg_side<<<NAGG, 512, 0, stream>>>(xc_hi, rp_a, col_c2a, xa_old,
                                           Wl_a2c + l * D * D, Wl_c2a + l * D * D,
                                           Wr_c2a + l * D * D, b_c2a + l * D, ya_bf, xa);
        gemm_mfma<<<625, 256, 0, stream>>>(
            (const unsigned short*)xc_hi, (const unsigned short*)xc_lo,
            Wt + l * 2 * D * D, b_a2c + l * D, Yb);
        if (l < NLAYER - 1) {
            agg_c_bf<0><<<(NCLI + 3) / 4, 256, 0, stream>>>((const unsigned*)ya_bf, rp_c, col_a2c,
                                                            Yb, xc_hi, xc_lo, nullptr, nullptr,
                                                            nullptr, E);
        } else {
            agg_c_bf<1><<<(NCLI + 3) / 4, 256, 0, stream>>>((const unsigned*)ya_bf, rp_c, col_a2c,
                                                            Yb, nullptr, nullptr, W_lin, b_lin,
                                                            out, E);
        }
        xa_old = xa;
    }
}

// Round 11
// 633.781 us; speedup vs baseline: 1.2309x; 1.1008x over previous
//
#include <hip/hip_runtime.h>

#define D      128
#define NCLI   100000
#define NAGG   1000
#define NLAYER 3
#define NBKT   782   // ceil(NCLI/128) buckets for a2c
#define NRNG   8     // src ranges for c2a CSR (12500 clients each, 3.2 MB slice/XCD-L2)
#define NBIN   (NAGG * NRNG)   // 8000
#define RMAGIC 343598u         // ceil(2^32/12500): r = umulhi(src, RMAGIC), exact for src<100000
#define NHIST  512
#define NCVTX  (NCLI * D / 4 / 256)   // 12500
#define NCVTW  ((NLAYER * D * D + 255) / 256)  // 192
#define NROWT  (NCLI / 32)            // 3125 row-tiles (exact)

typedef short bf16x8 __attribute__((ext_vector_type(8)));
typedef float f32x16 __attribute__((ext_vector_type(16)));

static __device__ __forceinline__ float leaky(float x) { return x >= 0.f ? x : 0.1f * x; }

// ---- bf16 pack/unpack (RNE) ----
static __device__ __forceinline__ unsigned bf16_rn(float f) {
    unsigned u = __float_as_uint(f);
    return (u + 0x7fffu + ((u >> 16) & 1u)) >> 16;
}
static __device__ __forceinline__ float bf_val(unsigned h) { return __uint_as_float(h << 16); }
static __device__ __forceinline__ unsigned pack_bf2(float lo, float hi) {
    return bf16_rn(lo) | (bf16_rn(hi) << 16);
}
static __device__ __forceinline__ float bf_lo(unsigned v) { return __uint_as_float(v << 16); }
static __device__ __forceinline__ float bf_hi(unsigned v) { return __uint_as_float(v & 0xffff0000u); }

// ---------------- phase 1: hist + feature/weight cvt, one launch ----------------
__global__ __launch_bounds__(256) void prep(const int* __restrict__ c2a_src,
                                            const int* __restrict__ c2a_dst,
                                            const int* __restrict__ a2c_dst, int E,
                                            int* __restrict__ cnt_ar, int* __restrict__ bcnt,
                                            const float4* __restrict__ X4,
                                            uint2* __restrict__ xhi, uint2* __restrict__ xlo,
                                            const float* __restrict__ W,
                                            unsigned short* __restrict__ Wt) {
    __shared__ int h[NBIN + NBKT];   // 35 KB
    int bid = blockIdx.x;
    if (bid < NHIST) {
        for (int i = threadIdx.x; i < NBIN + NBKT; i += 256) h[i] = 0;
        __syncthreads();
        int stride = NHIST * 256;
        for (int e = bid * 256 + threadIdx.x; e < E; e += stride) {
            int s = c2a_src[e];
            int bin = c2a_dst[e] * NRNG + (int)__umulhi((unsigned)s, RMAGIC);
            atomicAdd(&h[bin], 1);
            atomicAdd(&h[NBIN + (a2c_dst[e] >> 7)], 1);
        }
        __syncthreads();
        for (int i = threadIdx.x; i < NBIN; i += 256)
            if (h[i]) atomicAdd(&cnt_ar[i], h[i]);
        for (int i = threadIdx.x; i < NBKT; i += 256)
            if (h[NBIN + i]) atomicAdd(&bcnt[i], h[NBIN + i]);
    } else if (bid < NHIST + NCVTX) {
        int t = (bid - NHIST) * 256 + threadIdx.x;
        float4 f = X4[t];
        unsigned h0 = bf16_rn(f.x), h1 = bf16_rn(f.y), h2 = bf16_rn(f.z), h3 = bf16_rn(f.w);
        xhi[t] = make_uint2(h0 | (h1 << 16), h2 | (h3 << 16));
        xlo[t] = make_uint2(pack_bf2(f.x - bf_val(h0), f.y - bf_val(h1)),
                            pack_bf2(f.z - bf_val(h2), f.w - bf_val(h3)));
    } else {
        int idx = (bid - NHIST - NCVTX) * 256 + threadIdx.x;
        if (idx >= NLAYER * D * D) return;
        int layer = idx >> 14, rem = idx & (D * D - 1);
        int k = rem >> 7, n = rem & 127;
        float w = W[layer * D * D + k * D + n];
        unsigned hh = bf16_rn(w);
        unsigned short* base = Wt + layer * 2 * D * D;
        base[n * D + k] = (unsigned short)hh;
        base[D * D + n * D + k] = (unsigned short)bf16_rn(w - bf_val(hh));
    }
}

// ---------------- phase 2: scans ----------------
// block 0: scan cnt_ar[8000] -> rp_ar[8001] (starts) + cur_ar[8000]
// block 1: scan bcnt[782]    -> brp[783] + bcur[782]   (old convention)
__global__ void scan_both(const int* __restrict__ cnt_ar, int* __restrict__ rp_ar,
                          int* __restrict__ cur_ar, const int* __restrict__ bcnt,
                          int* __restrict__ brp, int* __restrict__ bcur) {
    __shared__ int sh[1024];
    int t = threadIdx.x;
    if (blockIdx.x == 0) {
        int v[8];
        int s = 0;
#pragma unroll
        for (int j = 0; j < 8; j++) {
            int idx = t * 8 + j;
            v[j] = (idx < NBIN) ? cnt_ar[idx] : 0;
            s += v[j];
        }
        sh[t] = s;
        __syncthreads();
        for (int off = 1; off < 1024; off <<= 1) {
            int x = (t >= off) ? sh[t - off] : 0;
            __syncthreads();
            sh[t] += x;
            __syncthreads();
        }
        int run = sh[t] - s;  // exclusive prefix of this thread's chunk
#pragma unroll
        for (int j = 0; j < 8; j++) {
            int idx = t * 8 + j;
            if (idx < NBIN) {
                rp_ar[idx] = run;
                cur_ar[idx] = run;
            }
            run += v[j];
        }
        if (t == 1023) rp_ar[NBIN] = sh[1023];
    } else {
        int v = (t < NBKT) ? bcnt[t] : 0;
        sh[t] = v;
        __syncthreads();
        for (int off = 1; off < 1024; off <<= 1) {
            int x = (t >= off) ? sh[t - off] : 0;
            __syncthreads();
            sh[t] += x;
            __syncthreads();
        }
        if (t == 0) { brp[0] = 0; bcur[0] = 0; }
        if (t < NBKT) {
            brp[t + 1] = sh[t];
            if (t + 1 < NBKT) bcur[t + 1] = sh[t];
        }
    }
}

// ---------------- phase 3: both scatters, one launch, 1024 threads ----------------
// blocks [0,256): c2a -> col_c2a grouped by bin=(dst*8+range), payload = src
// blocks [256,512): a2c -> sorted1 bucketed by dst>>7, payload = (dst&127)<<10 | src
__global__ __launch_bounds__(1024) void scatter_both(const int* __restrict__ c2a_src,
                                                     const int* __restrict__ c2a_dst,
                                                     const int* __restrict__ a2c_src,
                                                     const int* __restrict__ a2c_dst, int E,
                                                     int* __restrict__ cur_ar,
                                                     int* __restrict__ col_c2a,
                                                     int* __restrict__ bcur,
                                                     int* __restrict__ sorted1) {
    __shared__ int sbuf[2 * NBIN];   // 64 KB; a2c half reuses the front
    int tid = threadIdx.x;
    if (blockIdx.x < 256) {
        int* h = sbuf;
        int* base = sbuf + NBIN;
        int chunk = (E + 255) / 256;
        int e0 = blockIdx.x * chunk;
        int e1 = min(E, e0 + chunk);
        for (int i = tid; i < NBIN; i += 1024) h[i] = 0;
        __syncthreads();
        for (int e = e0 + tid; e < e1; e += 1024) {
            int s = c2a_src[e];
            atomicAdd(&h[c2a_dst[e] * NRNG + (int)__umulhi((unsigned)s, RMAGIC)], 1);
        }
        __syncthreads();
        for (int i = tid; i < NBIN; i += 1024) {
            int c = h[i];
            base[i] = c ? atomicAdd(&cur_ar[i], c) : 0;
        }
        __syncthreads();
        for (int e = e0 + tid; e < e1; e += 1024) {
            int s = c2a_src[e];
            int bin = c2a_dst[e] * NRNG + (int)__umulhi((unsigned)s, RMAGIC);
            int pos = atomicAdd(&base[bin], 1);
            col_c2a[pos] = s;
        }
    } else {
        int* h = sbuf;
        int* base = sbuf + NBKT;
        int bid = blockIdx.x - 256;
        int chunk = (E + 255) / 256;
        int e0 = bid * chunk;
        int e1 = min(E, e0 + chunk);
        for (int i = tid; i < NBKT; i += 1024) h[i] = 0;
        __syncthreads();
        for (int e = e0 + tid; e < e1; e += 1024) atomicAdd(&h[a2c_dst[e] >> 7], 1);
        __syncthreads();
        for (int i = tid; i < NBKT; i += 1024) {
            int c = h[i];
            base[i] = c ? atomicAdd(&bcur[i], c) : 0;
        }
        __syncthreads();
        for (int e = e0 + tid; e < e1; e += 1024) {
            int d = a2c_dst[e];
            int pos = atomicAdd(&base[d >> 7], 1);
            sorted1[pos] = ((d & 127) << 10) | a2c_src[e];
        }
    }
}

// ---------------- phase 4: per-bucket client CSR (a2c) ----------------
__global__ __launch_bounds__(512) void bucket_csr(const int* __restrict__ brp,
                                                  const int* __restrict__ sorted1,
                                                  int* __restrict__ rp_c,
                                                  int* __restrict__ col) {
    __shared__ int h[128], cur[128];
    int b = blockIdx.x, tid = threadIdx.x;
    if (tid < 128) h[tid] = 0;
    __syncthreads();
    int beg = brp[b], end = brp[b + 1];
    for (int e = beg + tid; e < end; e += 512) atomicAdd(&h[sorted1[e] >> 10], 1);
    __syncthreads();
    if (tid < 128) cur[tid] = h[tid];
    __syncthreads();
    for (int off = 1; off < 128; off <<= 1) {
        int x = 0;
        if (tid < 128 && tid >= off) x = cur[tid - off];
        __syncthreads();
        if (tid < 128) cur[tid] += x;
        __syncthreads();
    }
    if (tid < 128) {
        int start = beg + cur[tid] - h[tid];
        int c = b * 128 + tid;
        if (c < NCLI) rp_c[c] = start;
        cur[tid] = start;
    }
    if (b == NBKT - 1 && tid == 0) rp_c[NCLI] = end;
    __syncthreads();
    for (int e = beg + tid; e < end; e += 512) {
        int p = sorted1[e];
        int pos = atomicAdd(&cur[p >> 10], 1);
        col[pos] = p & 1023;
    }
}

// ---------------- layer kernels ----------------

// XCD-sliced mean gather: blockIdx = quad*8 + range; round-robin dispatch pins each
// src-range (3.2 MB table slice) to one XCD's L2. Block: 4 aggs x 8 readers x 16 lanes.
// Writes f32 partials psum[agg][range][128] (no atomics).
__global__ __launch_bounds__(512) void gather_mean(const unsigned* __restrict__ tbl,
                                                   const int* __restrict__ rp_ar,
                                                   const int* __restrict__ col,
                                                   float* __restrict__ psum) {
    __shared__ float part[4][8][D];   // 16 KB
    int quad = blockIdx.x >> 3, r = blockIdx.x & 7;
    int tid = threadIdx.x;
    int a = tid >> 7;            // local agg 0..3
    int sub = (tid >> 4) & 7;    // reader 0..7
    int sl = tid & 15;           // lane in reader
    const uint4* tbl4 = (const uint4*)tbl;
    int agg = quad * 4 + a;
    int bin = agg * NRNG + r;
    int beg = rp_ar[bin], end = rp_ar[bin + 1];
    float f0 = 0, f1 = 0, f2 = 0, f3 = 0, f4 = 0, f5 = 0, f6 = 0, f7 = 0;
    int e = beg + sub;
    for (; e + 8 < end; e += 16) {   // 2 edges in flight per reader
        int s0 = col[e];
        int s1 = col[e + 8];
        uint4 v0 = tbl4[(s0 << 4) + sl];
        uint4 v1 = tbl4[(s1 << 4) + sl];
        f0 += bf_lo(v0.x); f1 += bf_hi(v0.x); f2 += bf_lo(v0.y); f3 += bf_hi(v0.y);
        f4 += bf_lo(v0.z); f5 += bf_hi(v0.z); f6 += bf_lo(v0.w); f7 += bf_hi(v0.w);
        f0 += bf_lo(v1.x); f1 += bf_hi(v1.x); f2 += bf_lo(v1.y); f3 += bf_hi(v1.y);
        f4 += bf_lo(v1.z); f5 += bf_hi(v1.z); f6 += bf_lo(v1.w); f7 += bf_hi(v1.w);
    }
    if (e < end) {
        int s0 = col[e];
        uint4 v0 = tbl4[(s0 << 4) + sl];
        f0 += bf_lo(v0.x); f1 += bf_hi(v0.x); f2 += bf_lo(v0.y); f3 += bf_hi(v0.y);
        f4 += bf_lo(v0.z); f5 += bf_hi(v0.z); f6 += bf_lo(v0.w); f7 += bf_hi(v0.w);
    }
    float* pr = &part[a][sub][sl * 8];
    pr[0] = f0; pr[1] = f1; pr[2] = f2; pr[3] = f3;
    pr[4] = f4; pr[5] = f5; pr[6] = f6; pr[7] = f7;
    __syncthreads();
    int c = tid & 127;
    float s = 0.f;
#pragma unroll
    for (int g = 0; g < 8; g++) s += part[a][g][c];
    psum[((size_t)agg * NRNG + r) * D + c] = s;
}

// combine partials -> mean; then ya = xa@Wl_a2c (bf16), xa_new = leaky(mean@Wl_c2a + xa@Wr_c2a + b)
__global__ __launch_bounds__(128) void combine_agg(const float* __restrict__ psum,
                                                   const int* __restrict__ rp_ar,
                                                   const float* xa_old,
                                                   const float* __restrict__ Wl_a2c,
                                                   const float* __restrict__ Wl_c2a,
                                                   const float* __restrict__ Wr_c2a,
                                                   const float* __restrict__ b_c2a,
                                                   unsigned short* __restrict__ ya_bf,
                                                   float* xa_out) {
    __shared__ float mr[D], xr[D];
    int i = blockIdx.x, j = threadIdx.x;
    const float* pr = psum + (size_t)i * NRNG * D + j;
    float s = 0.f;
#pragma unroll
    for (int r = 0; r < NRNG; r++) s += pr[r * D];
    int deg = rp_ar[i * NRNG + NRNG] - rp_ar[i * NRNG];
    mr[j] = s / fmaxf((float)deg, 1.f);
    xr[j] = xa_old[i * D + j];
    __syncthreads();
    float accy = 0.f, accn = b_c2a[j];
#pragma unroll 4
    for (int k = 0; k < D; k++) {
        accy += xr[k] * Wl_a2c[k * D + j];
        accn += mr[k] * Wl_c2a[k * D + j] + xr[k] * Wr_c2a[k * D + j];
    }
    ya_bf[i * D + j] = (unsigned short)bf16_rn(accy);
    xa_out[i * D + j] = leaky(accn);
}

// Persistent split-bf16 MFMA gemm, 32x32x16 (R10-proven). B fragments register-resident.
__global__ __launch_bounds__(256) void gemm_mfma(const unsigned short* __restrict__ Ahi,
                                                 const unsigned short* __restrict__ Alo,
                                                 const unsigned short* __restrict__ Wt,
                                                 const float* __restrict__ bias,
                                                 float* __restrict__ Y) {
    int tid = threadIdx.x;
    int wave = tid >> 6, lane = tid & 63;
    int cl = lane & 31, kh = lane >> 5;
    int n0 = wave * 32;
    const unsigned short* Wlo = Wt + D * D;
    const unsigned short* wbh = Wt + (size_t)(n0 + cl) * D + kh * 8;
    const unsigned short* wbl = Wlo + (size_t)(n0 + cl) * D + kh * 8;
    bf16x8 bhi[8], blo[8];
#pragma unroll
    for (int kc = 0; kc < 8; kc++) {
        bhi[kc] = *(const bf16x8*)(wbh + kc * 16);
        blo[kc] = *(const bf16x8*)(wbl + kc * 16);
    }
    float bv = bias[n0 + cl];
    for (int r = blockIdx.x; r < NROWT; r += gridDim.x) {
        int m0 = r * 32;
        const unsigned short* ar = Ahi + (size_t)(m0 + cl) * D + kh * 8;
        const unsigned short* al = Alo + (size_t)(m0 + cl) * D + kh * 8;
        bf16x8 ahi[8], alo[8];
#pragma unroll
        for (int kc = 0; kc < 8; kc++) {
            ahi[kc] = *(const bf16x8*)(ar + kc * 16);
            alo[kc] = *(const bf16x8*)(al + kc * 16);
        }
        f32x16 acc;
#pragma unroll
        for (int q = 0; q < 16; q++) acc[q] = bv;
#pragma unroll
        for (int kc = 0; kc < 8; kc++) {
            acc = __builtin_amdgcn_mfma_f32_32x32x16_bf16(ahi[kc], bhi[kc], acc, 0, 0, 0);
            acc = __builtin_amdgcn_mfma_f32_32x32x16_bf16(alo[kc], bhi[kc], acc, 0, 0, 0);
            acc = __builtin_amdgcn_mfma_f32_32x32x16_bf16(ahi[kc], blo[kc], acc, 0, 0, 0);
        }
        float* yb = Y + (size_t)m0 * D + n0 + cl;
#pragma unroll
        for (int reg = 0; reg < 16; reg++) {
            int row = (reg & 3) + 8 * (reg >> 2) + 4 * kh;
            yb[(size_t)row * D] = acc[reg];
        }
    }
}

// xc = leaky(Yb + mean_e ya_bf[col[e]]) — R7-proven scalar version.
template <int LAST>
__global__ __launch_bounds__(256) void agg_c_bf(const unsigned* __restrict__ ya,
                                                const int* __restrict__ rowptr,
                                                const int* __restrict__ col,
                                                const float* __restrict__ Y,
                                                unsigned* __restrict__ xhi,
                                                unsigned* __restrict__ xlo,
                                                const float* __restrict__ Wlin,
                                                const float* __restrict__ blin,
                                                float* __restrict__ out, int E) {
    int l = threadIdx.x & 63;
    int gid = blockIdx.x * 4 + (threadIdx.x >> 6);
    if (gid >= NCLI) return;
    int beg = rowptr[gid], end = rowptr[gid + 1];
    float a0 = 0, b0 = 0, a1 = 0, b1 = 0, a2 = 0, b2 = 0, a3 = 0, b3 = 0;
    float a4 = 0, b4 = 0, a5 = 0, b5 = 0, a6 = 0, b6 = 0, a7 = 0, b7 = 0;
    for (int ch = beg; ch < end; ch += 64) {
        int len = min(64, end - ch);
        int ec = col[min(ch + l, E - 1)];
        int j = 0;
        for (; j + 8 <= len; j += 8) {
            int r0 = __shfl(ec, j + 0), r1 = __shfl(ec, j + 1);
            int r2 = __shfl(ec, j + 2), r3 = __shfl(ec, j + 3);
            int r4 = __shfl(ec, j + 4), r5 = __shfl(ec, j + 5);
            int r6 = __shfl(ec, j + 6), r7 = __shfl(ec, j + 7);
            unsigned v0 = ya[(r0 << 6) + l];
            unsigned v1 = ya[(r1 << 6) + l];
            unsigned v2 = ya[(r2 << 6) + l];
            unsigned v3 = ya[(r3 << 6) + l];
            unsigned v4 = ya[(r4 << 6) + l];
            unsigned v5 = ya[(r5 << 6) + l];
            unsigned v6 = ya[(r6 << 6) + l];
            unsigned v7 = ya[(r7 << 6) + l];
            a0 += bf_lo(v0); b0 += bf_hi(v0);
            a1 += bf_lo(v1); b1 += bf_hi(v1);
            a2 += bf_lo(v2); b2 += bf_hi(v2);
            a3 += bf_lo(v3); b3 += bf_hi(v3);
            a4 += bf_lo(v4); b4 += bf_hi(v4);
            a5 += bf_lo(v5); b5 += bf_hi(v5);
            a6 += bf_lo(v6); b6 += bf_hi(v6);
            a7 += bf_lo(v7); b7 += bf_hi(v7);
        }
        for (; j < len; j++) {
            int r = __shfl(ec, j);
            unsigned v = ya[(r << 6) + l];
            a0 += bf_lo(v); b0 += bf_hi(v);
        }
    }
    float sx = ((a0 + a1) + (a2 + a3)) + ((a4 + a5) + (a6 + a7));
    float sy = ((b0 + b1) + (b2 + b3)) + ((b4 + b5) + (b6 + b7));
    float inv = 1.f / fmaxf((float)(end - beg), 1.f);
    float2 yv = *(const float2*)&Y[(size_t)gid * D + 2 * l];
    float r0 = leaky(yv.x + sx * inv);
    float r1 = leaky(yv.y + sy * inv);
    if (LAST) {
        float2 w = *(const float2*)&Wlin[2 * l];
        float v = r0 * w.x + r1 * w.y;
#pragma unroll
        for (int off = 32; off > 0; off >>= 1) v += __shfl_down(v, off);
        if (l == 0) out[gid] = v + blin[0];
    } else {
        unsigned h0 = bf16_rn(r0), h1 = bf16_rn(r1);
        xhi[(gid << 6) + l] = h0 | (h1 << 16);
        xlo[(gid << 6) + l] = pack_bf2(r0 - bf_val(h0), r1 - bf_val(h1));
    }
}

extern "C" void kernel_launch(void* const* d_in, const int* in_sizes, int n_in,
                              void* d_out, int out_size, void* d_ws, size_t ws_size,
                              hipStream_t stream) {
    const float* x_clients = (const float*)d_in[0];
    const float* x_agg     = (const float*)d_in[1];
    const int*   c2a_src   = (const int*)d_in[2];
    const int*   c2a_dst   = (const int*)d_in[3];
    const int*   a2c_src   = (const int*)d_in[4];
    const int*   a2c_dst   = (const int*)d_in[5];
    const float* Wl_c2a    = (const float*)d_in[6];
    const float* Wr_c2a    = (const float*)d_in[7];
    const float* b_c2a     = (const float*)d_in[8];
    const float* Wl_a2c    = (const float*)d_in[9];
    const float* Wr_a2c    = (const float*)d_in[10];
    const float* b_a2c     = (const float*)d_in[11];
    const float* W_lin     = (const float*)d_in[12];
    const float* b_lin     = (const float*)d_in[13];
    float* out = (float*)d_out;
    const int E = in_sizes[2];

    char* p = (char*)d_ws;
    auto alloc = [&](size_t bytes) {
        char* r = p;
        p += (bytes + 255) & ~(size_t)255;
        return r;
    };
    float*    Yb    = (float*)alloc(sizeof(float) * NCLI * D);         // gemm output (f32)
    unsigned* xc_hi = (unsigned*)alloc(sizeof(unsigned) * NCLI * 64);  // bf16 hi (also gather tbl)
    unsigned* xc_lo = (unsigned*)alloc(sizeof(unsigned) * NCLI * 64);  // bf16 lo
    float*    xa    = (float*)alloc(sizeof(float) * NAGG * D);
    unsigned short* ya_bf = (unsigned short*)alloc(sizeof(unsigned short) * NAGG * D);
    unsigned short* Wt = (unsigned short*)alloc(sizeof(unsigned short) * NLAYER * 2 * D * D);
    float* psum  = (float*)alloc(sizeof(float) * NAGG * NRNG * D);     // 4 MB gather partials
    int* cnt_ar = (int*)alloc(sizeof(int) * (NBIN + NBKT));  // cnt_ar[0..7999] + bcnt
    int* bcnt  = cnt_ar + NBIN;
    int* rp_ar = (int*)alloc(sizeof(int) * (NBIN + 1));
    int* cur_ar = (int*)alloc(sizeof(int) * NBIN);
    int* brp   = (int*)alloc(sizeof(int) * (NBKT + 1));
    int* bcur  = (int*)alloc(sizeof(int) * NBKT);
    int* rp_c  = (int*)alloc(sizeof(int) * (NCLI + 1));
    int* col_c2a = (int*)alloc(sizeof(int) * E);
    int* col_a2c = (int*)alloc(sizeof(int) * E);
    // sorted1 aliases Yb: lifetime disjoint (CSR build completes before layer-0 gemm writes Yb)
    int* sorted1 = (int*)Yb;

    hipMemsetAsync(cnt_ar, 0, sizeof(int) * (NBIN + NBKT), stream);

    prep<<<NHIST + NCVTX + NCVTW, 256, 0, stream>>>(c2a_src, c2a_dst, a2c_dst, E, cnt_ar, bcnt,
                                                    (const float4*)x_clients,
                                                    (uint2*)xc_hi, (uint2*)xc_lo,
                                                    Wr_a2c, Wt);
    scan_both<<<2, 1024, 0, stream>>>(cnt_ar, rp_ar, cur_ar, bcnt, brp, bcur);
    scatter_both<<<512, 1024, 0, stream>>>(c2a_src, c2a_dst, a2c_src, a2c_dst, E,
                                           cur_ar, col_c2a, bcur, sorted1);
    bucket_csr<<<NBKT, 512, 0, stream>>>(brp, sorted1, rp_c, col_a2c);

    const float* xa_old = x_agg;
    for (int l = 0; l < NLAYER; l++) {
        // agg side: XCD-sliced gather -> partials -> combine (+ ya, xa update)
        gather_mean<<<(NAGG / 4) * NRNG, 512, 0, stream>>>(xc_hi, rp_ar, col_c2a, psum);
        combine_agg<<<NAGG, 128, 0, stream>>>(psum, rp_ar, xa_old,
                                              Wl_a2c + l * D * D, Wl_c2a + l * D * D,
                                              Wr_c2a + l * D * D, b_c2a + l * D, ya_bf, xa);
        gemm_mfma<<<625, 256, 0, stream>>>(
            (const unsigned short*)xc_hi, (const unsigned short*)xc_lo,
            Wt + l * 2 * D * D, b_a2c + l * D, Yb);
        if (l < NLAYER - 1) {
            agg_c_bf<0><<<(NCLI + 3) / 4, 256, 0, stream>>>((const unsigned*)ya_bf, rp_c, col_a2c,
                                                            Yb, xc_hi, xc_lo, nullptr, nullptr,
                                                            nullptr, E);
        } else {
            agg_c_bf<1><<<(NCLI + 3) / 4, 256, 0, stream>>>((const unsigned*)ya_bf, rp_c, col_a2c,
                                                            Yb, nullptr, nullptr, W_lin, b_lin,
                                                            out, E);
        }
        xa_old = xa;
    }
}